// Round 4
// baseline (42.597 us; speedup 1.0000x reference)
//
#include <hip/hip_runtime.h>

#define BATCH 8
#define NPTS  4096
#define BLOCK 256
#define Q     16             // query points per thread (covers all 4096/block)
#define CHUNK 128            // target points staged in LDS per block
#define NPER  32768          // BATCH*NPTS points per cloud

// ws layout:
//   float4 pk[65536]    : packed [x,y,z,|p|^2]; pred at [b*4096+n], gt at 32768+...
//   uint   minbuf[65536]: min d2 bits; pred-queries first, gt-queries second

// K0: pack points into float4 (xyz + squared norm) and init min slots to +inf.
__global__ __launch_bounds__(256) void pack_init_kernel(
    const float* __restrict__ pred, const float* __restrict__ gt,
    float4* __restrict__ pk, unsigned int* __restrict__ minbuf)
{
    const int j = blockIdx.x * 256 + threadIdx.x;     // 0..65535
    const float* src = (j < NPER) ? pred : gt;
    const float* p = src + (size_t)(j & (NPER - 1)) * 3;
    const float x = p[0], y = p[1], z = p[2];
    pk[j] = make_float4(x, y, z, fmaf(x, x, fmaf(y, y, z * z)));
    minbuf[j] = 0x7F800000u;                          // +inf
}

// K1: grid (1, NPTS/CHUNK, 16). Each thread owns Q=16 queries (i*BLOCK+tid),
// loops over CHUNK targets staged in LDS as [gx,gy,gz,g2]. Tracks
// min(g2 - 2 p.g) with 3 fma per pair + min3 per 2 pairs; folds |p|^2 after.
__global__ __launch_bounds__(BLOCK) void chamfer_min_kernel(
    const float4* __restrict__ pk, unsigned int* __restrict__ minbuf)
{
    const int z    = blockIdx.z;
    const int b    = z & 7;
    const int pass = z >> 3;
    const float4* query  = pk + (pass ? NPER : 0) + b * NPTS;
    const float4* target = pk + (pass ? 0 : NPER) + b * NPTS;
    unsigned int* outmin = minbuf + (pass ? NPER : 0) + b * NPTS;

    __shared__ float4 s[CHUNK];

    const int tid = threadIdx.x;
    const int c0  = blockIdx.y * CHUNK;

    if (tid < CHUNK) s[tid] = target[c0 + tid];

    float nx2[Q], ny2[Q], nz2[Q], p2[Q], mn[Q];
#pragma unroll
    for (int i = 0; i < Q; ++i) {
        const float4 qf = query[i * BLOCK + tid];
        nx2[i] = -2.0f * qf.x;
        ny2[i] = -2.0f * qf.y;
        nz2[i] = -2.0f * qf.z;
        p2[i]  = qf.w;
        mn[i]  = 3.0e38f;
    }
    __syncthreads();

#pragma unroll 2
    for (int t = 0; t < CHUNK; t += 2) {
        const float4 g0 = s[t];
        const float4 g1 = s[t + 1];
#pragma unroll
        for (int i = 0; i < Q; ++i) {
            float da = fmaf(g0.x, nx2[i], g0.w);
            da = fmaf(g0.y, ny2[i], da);
            da = fmaf(g0.z, nz2[i], da);
            float db = fmaf(g1.x, nx2[i], g1.w);
            db = fmaf(g1.y, ny2[i], db);
            db = fmaf(g1.z, nz2[i], db);
            mn[i] = fminf(mn[i], fminf(da, db));      // -> v_min3_f32
        }
    }

#pragma unroll
    for (int i = 0; i < Q; ++i) {
        const float d2 = fmaxf(p2[i] + mn[i], 0.0f);  // min squared distance
        atomicMin(&outmin[i * BLOCK + tid], __float_as_uint(d2));
    }
}

// K2: deterministic single-block reduction: (sum sqrt(min d2))/32768.
__global__ __launch_bounds__(1024) void chamfer_reduce_kernel(
    const uint4* __restrict__ mins,                   // 65536 uints = 16384 uint4
    float* __restrict__ out)
{
    const int tid = threadIdx.x;
    double acc = 0.0;
#pragma unroll
    for (int i = 0; i < 16; ++i) {
        const uint4 v = mins[tid + i * 1024];
        acc += (double)(sqrtf(__uint_as_float(v.x)) + sqrtf(__uint_as_float(v.y))
                      + sqrtf(__uint_as_float(v.z)) + sqrtf(__uint_as_float(v.w)));
    }
    __shared__ double sd[1024];
    sd[tid] = acc;
    __syncthreads();
    for (int off = 512; off > 0; off >>= 1) {
        if (tid < off) sd[tid] += sd[tid + off];
        __syncthreads();
    }
    if (tid == 0) out[0] = (float)(sd[0] / (double)NPER);
}

extern "C" void kernel_launch(void* const* d_in, const int* in_sizes, int n_in,
                              void* d_out, int out_size, void* d_ws, size_t ws_size,
                              hipStream_t stream) {
    const float* pred = (const float*)d_in[0];
    const float* gt   = (const float*)d_in[1];

    float4* pk           = (float4*)d_ws;                   // 65536 float4 = 1 MB
    unsigned int* minbuf = (unsigned int*)(pk + 2 * NPER);  // 256 KB

    pack_init_kernel<<<2 * NPER / 256, 256, 0, stream>>>(pred, gt, pk, minbuf);

    dim3 grid(1, NPTS / CHUNK, 2 * BATCH);
    chamfer_min_kernel<<<grid, BLOCK, 0, stream>>>(pk, minbuf);

    chamfer_reduce_kernel<<<1, 1024, 0, stream>>>((const uint4*)minbuf, (float*)d_out);
}